// Round 3
// baseline (293.145 us; speedup 1.0000x reference)
//
#include <hip/hip_runtime.h>
#include <hip/hip_bf16.h>
#include <stdint.h>

// Problem constants
#define B_SZ   1024
#define GF     512     // gating features
#define GC     63      // gate count
#define NLEAF  64
#define IN_F   512
#define OUT_F  512

#define SPLITK 8
#define KI     64      // i-steps per block (512 / SPLITK)

typedef float f32x4 __attribute__((ext_vector_type(4)));
typedef __bf16 bf16x8 __attribute__((ext_vector_type(8)));

struct alignas(16) BV8 { __hip_bfloat162 a, b, c, d; };  // 8 bf16 = 16B
union PK8 { BV8 v; bf16x8 f; };
union BU { __hip_bfloat162 h; unsigned int u; };

// ---------------------------------------------------------------------------
// Kernel 1: gatings = sigmoid(x_gating @ gw + gb); leaf_probs via tree product
// ---------------------------------------------------------------------------
__global__ __launch_bounds__(512, 2) void k_leafprobs(
    const float* __restrict__ xg, const float* __restrict__ gw,
    const float* __restrict__ gb, float* __restrict__ p_ws)
{
  __shared__ float xsr[GF];
  __shared__ float part[512];
  __shared__ float gates[GC + 1];
  const int b = blockIdx.x;
  const int t = threadIdx.x;

  xsr[t] = xg[(size_t)b * GF + t];
  __syncthreads();

  const int ks = t >> 6;    // 0..7  (k-split)
  const int g  = t & 63;    // gate
  float acc = 0.f;
  if (g < GC) {
    const float* gp = gw + (size_t)(ks * 64) * GC + g;
    const float* xp = &xsr[ks * 64];
#pragma unroll 8
    for (int k = 0; k < 64; ++k) acc += xp[k] * gp[(size_t)k * GC];
  }
  part[t] = acc;
  __syncthreads();

  if (t < GC) {
    float s = gb[t];
#pragma unroll
    for (int r = 0; r < 8; ++r) s += part[r * 64 + t];
    gates[t] = 1.f / (1.f + expf(-s));
  }
  __syncthreads();

  if (t < NLEAF) {
    float v = 1.f;
    int idx = 0, start = 0;
#pragma unroll
    for (int d = 0; d < 6; ++d) {
      int bit = (t >> (5 - d)) & 1;
      float gg = gates[start + idx];
      v *= bit ? (1.f - gg) : gg;
      idx = 2 * idx + bit;
      start += (1 << d);
    }
    p_ws[(size_t)b * NLEAF + t] = v;
  }
}

// ---------------------------------------------------------------------------
// Kernel 2: convert pw (fp32, [o][i][l]) -> pwb (bf16, [i][o][l])
// ---------------------------------------------------------------------------
__global__ __launch_bounds__(256, 4) void k_convert(
    const float* __restrict__ pw, __hip_bfloat16* __restrict__ pwb)
{
  const int t  = blockIdx.x * 256 + threadIdx.x;   // 4,194,304 threads
  const int l4 = (t & 15) * 4;
  const int o  = (t >> 4) & 511;
  const int i  = t >> 13;

  float4 v = *(const float4*)(pw + ((size_t)o * IN_F + i) * NLEAF + l4);
  BU ua, ub;
  ua.h = __float22bfloat162_rn(make_float2(v.x, v.y));
  ub.h = __float22bfloat162_rn(make_float2(v.z, v.w));
  uint2 outv = make_uint2(ua.u, ub.u);
  *(uint2*)(pwb + (size_t)i * (OUT_F * NLEAF) + (size_t)o * NLEAF + l4) = outv;
}

// ---------------------------------------------------------------------------
// Kernel 3: main GEMM, barrier-free K-loop, direct global->VGPR B fragments.
// out[b][o] (+)= sum_{i,l} (x[b][i]*p[b][l]) * pwb[i][o][l]
// 128x128 MN tile, 8 waves (512 thr): wave = 32m x 64n quadrant.
// splitK=8 -> 256 blocks. Epilogue: plain stores to fp32 partials (ATOMIC=false)
// or atomicAdd onto bias-initialized out (ATOMIC=true fallback).
// ---------------------------------------------------------------------------
template <bool ATOMIC>
__global__ __launch_bounds__(512, 2) void k_gemm(
    const float* __restrict__ x_leaf,          // [1024][512]
    const float* __restrict__ p_ws,            // [1024][64]
    const __hip_bfloat16* __restrict__ pwb,    // [512][512][64]  ([i][o][l])
    float* __restrict__ dst)                   // parts [8][1024][512] or out
{
  __shared__ __align__(16) float xs[128][68];   // 34.8 KB; stride 68: 2-way max

  const int tid  = threadIdx.x;
  const int lane = tid & 63;
  const int wid  = tid >> 6;        // 0..7
  const int quad = lane >> 4;       // 0..3
  const int l15  = lane & 15;

  // XCD swizzle: blocks sharing (nt, kc-parity) land on one XCD
  const int bid = blockIdx.x;       // 256 blocks
  const int xcd = bid & 7;
  const int j   = bid >> 3;         // 0..31
  const int nt  = xcd >> 1;         // 0..3
  const int kcl = xcd & 1;
  const int mt  = j & 7;
  const int kch = j >> 3;           // 0..3
  const int kc  = kch * 2 + kcl;    // 0..7

  const int row_m0 = mt * 128;
  const int col_n0 = nt * 128;
  const int i0     = kc * KI;

  const int wm = (wid >> 1) * 32;   // wave's m-quadrant (32 rows)
  const int wn = (wid & 1) * 64;    // wave's n-half (64 cols)

  // ---- stage x slab [128 rows][64 i] ----
  {
    int r = tid >> 2, seg = tid & 3;
    const float* src = x_leaf + (size_t)(row_m0 + r) * IN_F + i0 + seg * 16;
    float4 v0 = *(const float4*)(src + 0);
    float4 v1 = *(const float4*)(src + 4);
    float4 v2 = *(const float4*)(src + 8);
    float4 v3 = *(const float4*)(src + 12);
    *(float4*)&xs[r][seg * 16 + 0]  = v0;
    *(float4*)&xs[r][seg * 16 + 4]  = v1;
    *(float4*)&xs[r][seg * 16 + 8]  = v2;
    *(float4*)&xs[r][seg * 16 + 12] = v3;
  }

  // ---- per-lane p fragment values fp32: pr[mi][ks][half4] (rows reused all K) ----
  f32x4 pr[2][2][2];
#pragma unroll
  for (int mi = 0; mi < 2; ++mi) {
    int row = row_m0 + wm + mi * 16 + l15;
#pragma unroll
    for (int ks = 0; ks < 2; ++ks) {
      const f32x4* src = (const f32x4*)(p_ws + (size_t)row * NLEAF + ks * 32 + quad * 8);
      pr[mi][ks][0] = src[0];
      pr[mi][ks][1] = src[1];
    }
  }

  f32x4 acc[2][4];
#pragma unroll
  for (int mi = 0; mi < 2; ++mi)
#pragma unroll
    for (int ni = 0; ni < 4; ++ni)
      acc[mi][ni] = (f32x4)(0.f);

  // per-lane B base: element (i0, col_n0+wn+l15, quad*8)
  const __hip_bfloat16* bb = pwb + ((size_t)i0 << 15)
                           + ((size_t)(col_n0 + wn + l15) << 6) + (quad << 3);

  __syncthreads();  // xs ready; no further barriers

#define LOADB(dstv, IOFF)                                                     \
  {                                                                           \
    const __hip_bfloat16* bp_ = bb + ((size_t)(IOFF) << 15);                  \
    _Pragma("unroll")                                                         \
    for (int ni_ = 0; ni_ < 4; ++ni_)                                         \
      _Pragma("unroll")                                                       \
      for (int ks_ = 0; ks_ < 2; ++ks_)                                       \
        dstv[ni_ * 2 + ks_] =                                                 \
            *(const bf16x8*)(bp_ + ni_ * 1024 + ks_ * 32);                    \
  }

#define COMPUTE(II, BV)                                                       \
  {                                                                           \
    float xv0 = xs[wm + l15][II];                                             \
    float xv1 = xs[wm + 16 + l15][II];                                        \
    _Pragma("unroll")                                                         \
    for (int ks_ = 0; ks_ < 2; ++ks_) {                                       \
      bf16x8 af0, af1;                                                        \
      {                                                                       \
        f32x4 lo = pr[0][ks_][0] * xv0, hi = pr[0][ks_][1] * xv0;             \
        PK8 u;                                                                \
        u.v.a = __float22bfloat162_rn(make_float2(lo.x, lo.y));               \
        u.v.b = __float22bfloat162_rn(make_float2(lo.z, lo.w));               \
        u.v.c = __float22bfloat162_rn(make_float2(hi.x, hi.y));               \
        u.v.d = __float22bfloat162_rn(make_float2(hi.z, hi.w));               \
        af0 = u.f;                                                            \
      }                                                                       \
      {                                                                       \
        f32x4 lo = pr[1][ks_][0] * xv1, hi = pr[1][ks_][1] * xv1;             \
        PK8 u;                                                                \
        u.v.a = __float22bfloat162_rn(make_float2(lo.x, lo.y));               \
        u.v.b = __float22bfloat162_rn(make_float2(lo.z, lo.w));               \
        u.v.c = __float22bfloat162_rn(make_float2(hi.x, hi.y));               \
        u.v.d = __float22bfloat162_rn(make_float2(hi.z, hi.w));               \
        af1 = u.f;                                                            \
      }                                                                       \
      _Pragma("unroll")                                                       \
      for (int ni_ = 0; ni_ < 4; ++ni_) {                                     \
        acc[0][ni_] = __builtin_amdgcn_mfma_f32_16x16x32_bf16(                \
            af0, BV[ni_ * 2 + ks_], acc[0][ni_], 0, 0, 0);                    \
        acc[1][ni_] = __builtin_amdgcn_mfma_f32_16x16x32_bf16(                \
            af1, BV[ni_ * 2 + ks_], acc[1][ni_], 0, 0, 0);                    \
      }                                                                       \
    }                                                                         \
  }

  // software-pipelined, barrier-free K-loop (unroll 2, reg double-buffer)
  bf16x8 b0[8], b1[8];
  LOADB(b0, 0)
  for (int ii = 0; ii < KI; ii += 2) {
    LOADB(b1, ii + 1)
    COMPUTE(ii, b0)
    if (ii + 2 < KI) LOADB(b0, ii + 2)
    COMPUTE(ii + 1, b1)
  }

  // ---- epilogue ----
#pragma unroll
  for (int mi = 0; mi < 2; ++mi) {
#pragma unroll
    for (int ni = 0; ni < 4; ++ni) {
      int row = row_m0 + wm + mi * 16 + quad * 4;
      int col = col_n0 + wn + ni * 16 + l15;
      if (ATOMIC) {
        float* o0 = dst + (size_t)row * OUT_F + col;
        atomicAdd(o0,             acc[mi][ni][0]);
        atomicAdd(o0 + OUT_F,     acc[mi][ni][1]);
        atomicAdd(o0 + 2 * OUT_F, acc[mi][ni][2]);
        atomicAdd(o0 + 3 * OUT_F, acc[mi][ni][3]);
      } else {
        float* o0 = dst + ((size_t)kc << 19) + (size_t)row * OUT_F + col;
        o0[0]         = acc[mi][ni][0];
        o0[OUT_F]     = acc[mi][ni][1];
        o0[2 * OUT_F] = acc[mi][ni][2];
        o0[3 * OUT_F] = acc[mi][ni][3];
      }
    }
  }
}

// ---------------------------------------------------------------------------
// Kernel 4: out[b][o] = sum_kc parts[kc][b][o] + sum_l p[b][l]*pb[o][l]
// nparts==0: bias-only init (atomic-fallback path).
// 256 blocks x 256 thr; block = 4 b-rows; thread = 2 rows x 4 cols.
// ---------------------------------------------------------------------------
__global__ __launch_bounds__(256, 4) void k_reduce(
    const float* __restrict__ parts, const float* __restrict__ p_ws,
    const float* __restrict__ pb, float* __restrict__ out, int nparts)
{
  __shared__ float ps_l[4 * NLEAF];
  const int t  = threadIdx.x;
  const int b0 = blockIdx.x * 4;

  if (t < 64)
    ((f32x4*)ps_l)[t] = ((const f32x4*)(p_ws + (size_t)b0 * NLEAF))[t];
  __syncthreads();

  const int c0 = (t & 127) * 4;
  const int r0 = (t >> 7) * 2;          // 0 or 2
  const f32x4* psA = (const f32x4*)&ps_l[(r0 + 0) * NLEAF];
  const f32x4* psB = (const f32x4*)&ps_l[(r0 + 1) * NLEAF];

  // bias terms for 2 rows x 4 cols
  float biasA[4], biasB[4];
#pragma unroll
  for (int jo = 0; jo < 4; ++jo) {
    const f32x4* pbo = (const f32x4*)(pb + (size_t)(c0 + jo) * NLEAF);
    f32x4 sA = (f32x4)(0.f), sB = (f32x4)(0.f);
#pragma unroll
    for (int lv = 0; lv < 16; ++lv) {
      f32x4 w = pbo[lv];
      sA += w * psA[lv];
      sB += w * psB[lv];
    }
    biasA[jo] = sA.x + sA.y + sA.z + sA.w;
    biasB[jo] = sB.x + sB.y + sB.z + sB.w;
  }

#pragma unroll
  for (int rr = 0; rr < 2; ++rr) {
    int row = b0 + r0 + rr;
    f32x4 a = (f32x4)(0.f);
    for (int kcp = 0; kcp < nparts; ++kcp)
      a += *(const f32x4*)(parts + ((size_t)kcp << 19) + (size_t)row * OUT_F + c0);
    a.x += rr ? biasB[0] : biasA[0];
    a.y += rr ? biasB[1] : biasA[1];
    a.z += rr ? biasB[2] : biasA[2];
    a.w += rr ? biasB[3] : biasA[3];
    *(f32x4*)(out + (size_t)row * OUT_F + c0) = a;
  }
}

// ---------------------------------------------------------------------------
extern "C" void kernel_launch(void* const* d_in, const int* in_sizes, int n_in,
                              void* d_out, int out_size, void* d_ws, size_t ws_size,
                              hipStream_t stream) {
  const float* xg = (const float*)d_in[0];   // x_gating [1024][512]
  const float* xl = (const float*)d_in[1];   // x_leaf   [1024][512]
  const float* gw = (const float*)d_in[2];   // [512][63]
  const float* gb = (const float*)d_in[3];   // [63]
  const float* pw = (const float*)d_in[4];   // [512][512][64]
  const float* pb = (const float*)d_in[5];   // [512][64]
  float* out = (float*)d_out;

  // ws layout: pwb bf16 (33,554,432 B) | p fp32 (262,144 B) | parts fp32 (16,777,216 B)
  const size_t PWB_BYTES = (size_t)IN_F * OUT_F * NLEAF * 2;
  const size_t P_BYTES   = (size_t)B_SZ * NLEAF * 4;
  const size_t PART_BYTES = (size_t)SPLITK * B_SZ * OUT_F * 4;

  __hip_bfloat16* pwb = (__hip_bfloat16*)d_ws;
  float* p_ws  = (float*)((char*)d_ws + PWB_BYTES);
  float* parts = (float*)((char*)d_ws + PWB_BYTES + P_BYTES);

  const bool have_parts = ws_size >= PWB_BYTES + P_BYTES + PART_BYTES;

  k_leafprobs<<<dim3(B_SZ), dim3(512), 0, stream>>>(xg, gw, gb, p_ws);
  k_convert<<<dim3(16384), dim3(256), 0, stream>>>(pw, pwb);

  if (have_parts) {
    k_gemm<false><<<dim3(256), dim3(512), 0, stream>>>(xl, p_ws, pwb, parts);
    k_reduce<<<dim3(256), dim3(256), 0, stream>>>(parts, p_ws, pb, out, SPLITK);
  } else {
    k_reduce<<<dim3(256), dim3(256), 0, stream>>>(parts, p_ws, pb, out, 0);
    k_gemm<true><<<dim3(256), dim3(512), 0, stream>>>(xl, p_ws, pwb, out);
  }
}

// Round 4
// 191.829 us; speedup vs baseline: 1.5282x; 1.5282x over previous
//
#include <hip/hip_runtime.h>
#include <hip/hip_bf16.h>
#include <stdint.h>

// Problem constants
#define B_SZ   1024
#define GF     512     // gating features
#define GC     63      // gate count
#define NLEAF  64
#define IN_F   512
#define OUT_F  512

typedef float f32x4 __attribute__((ext_vector_type(4)));
typedef __bf16 bf16x8 __attribute__((ext_vector_type(8)));

struct alignas(16) BV8 { __hip_bfloat162 a, b, c, d; };  // 8 bf16 = 16B
union PK8 { BV8 v; bf16x8 f; };
union BU { __hip_bfloat162 h; unsigned int u; };

// ---------------------------------------------------------------------------
// Kernel 1 (fused): blocks [0,1024) -> leaf_probs; blocks [1024,9216) ->
// pw fp32 [o][i][l] -> pwb bf16 [i][o][l] conversion. One launch, overlapped.
// ---------------------------------------------------------------------------
__global__ __launch_bounds__(512, 2) void k_prep(
    const float* __restrict__ xg, const float* __restrict__ gw,
    const float* __restrict__ gb, float* __restrict__ p_ws,
    const float* __restrict__ pw, __hip_bfloat16* __restrict__ pwb)
{
  __shared__ float xsr[GF];
  __shared__ float part[512];
  __shared__ float gates[GC + 1];
  const int blk = blockIdx.x;
  const int t   = threadIdx.x;

  if (blk < B_SZ) {
    // ---- leaf probs for batch row blk ----
    const int b = blk;
    xsr[t] = xg[(size_t)b * GF + t];
    __syncthreads();

    const int ks = t >> 6;    // 0..7  (k-split)
    const int g  = t & 63;    // gate
    float acc = 0.f;
    if (g < GC) {
      const float* gp = gw + (size_t)(ks * 64) * GC + g;
      const float* xp = &xsr[ks * 64];
#pragma unroll 8
      for (int k = 0; k < 64; ++k) acc += xp[k] * gp[(size_t)k * GC];
    }
    part[t] = acc;
    __syncthreads();

    if (t < GC) {
      float s = gb[t];
#pragma unroll
      for (int r = 0; r < 8; ++r) s += part[r * 64 + t];
      gates[t] = 1.f / (1.f + expf(-s));
    }
    __syncthreads();

    if (t < NLEAF) {
      float v = 1.f;
      int idx = 0, start = 0;
#pragma unroll
      for (int d = 0; d < 6; ++d) {
        int bit = (t >> (5 - d)) & 1;
        float gg = gates[start + idx];
        v *= bit ? (1.f - gg) : gg;
        idx = 2 * idx + bit;
        start += (1 << d);
      }
      p_ws[(size_t)b * NLEAF + t] = v;
    }
  } else {
    // ---- pw convert: thread tt handles 4 leaves of one (o,i) ----
    const int tt = (blk - B_SZ) * 512 + t;   // 0 .. 4,194,303
    const int l4 = (tt & 15) * 4;
    const int o  = (tt >> 4) & 511;
    const int i  = tt >> 13;

    float4 v = *(const float4*)(pw + ((size_t)o * IN_F + i) * NLEAF + l4);
    BU ua, ub;
    ua.h = __float22bfloat162_rn(make_float2(v.x, v.y));
    ub.h = __float22bfloat162_rn(make_float2(v.z, v.w));
    uint2 outv = make_uint2(ua.u, ub.u);
    *(uint2*)(pwb + (size_t)i * (OUT_F * NLEAF) + (size_t)o * NLEAF + l4) = outv;
  }
}

// ---------------------------------------------------------------------------
// Kernel 2: main GEMM.  out[b][o] (+)= sum_{i,l} (x[b][i]*p[b][l]) * pwb[i][o][l]
// BM=128, BN=64, 128-thr blocks (2 waves of 64m x 64n stacked on m).
// KI = 512/SK i-steps per block. grid = 8mt x 8nt x SK.
// B staged via glds (XOR-rotated), double-buffered, 1 barrier/i-step.
// A built in registers (p fp32 in VGPRs, x via LDS broadcast), single RN round.
// Small blocks -> many independent barriers per CU (occupancy fix for R2).
// XCD swizzle: the 8 mt-blocks sharing a (nt,kc) B-slice land on one XCD.
// ---------------------------------------------------------------------------
template <int SK, bool ATOMIC>
__global__ __launch_bounds__(128, 2) void k_gemm(
    const float* __restrict__ x_leaf,          // [1024][512]
    const float* __restrict__ p_ws,            // [1024][64]
    const __hip_bfloat16* __restrict__ pwb,    // [512][512][64]  ([i][o][l])
    float* __restrict__ dst)                   // parts [SK][1024][512] or out
{
  constexpr int KI   = 512 / SK;
  constexpr int XPAD = KI + 4;                 // 16B-aligned rows, gcd(XPAD,32)=4
  __shared__ __align__(16) float           xs[128][XPAD];
  __shared__ __align__(16) __hip_bfloat16  bs[2][64 * 64];   // 2 x 8 KB

  const int tid  = threadIdx.x;
  const int lane = tid & 63;
  const int wid  = tid >> 6;        // 0..1
  const int quad = lane >> 4;       // 0..3
  const int l15  = lane & 15;

  // XCD swizzle: xcd picks kc-low; 8 mt-blocks per (nt,kc) share an XCD's L2
  const int bid = blockIdx.x;
  const int xcd = bid & 7;
  const int idx = bid >> 3;
  const int mt  = idx & 7;
  const int r2  = idx >> 3;
  const int nt  = r2 & 7;
  const int kcg = r2 >> 3;          // 0..SK/8-1
  const int kc  = kcg * 8 + xcd;    // 0..SK-1

  const int row_m0 = mt * 128;
  const int col_n0 = nt * 64;
  const int i0     = kc * KI;

  const int wm = wid * 64;          // wave's 64-row half

  // ---- stage x slab [128 rows][KI i] ----
#pragma unroll
  for (int pass = 0; pass < KI / 4; ++pass) {
    int j = pass * 128 + tid;
    int r = j / (KI / 4);
    int c = j % (KI / 4);
    *(float4*)&xs[r][c * 4] =
        *(const float4*)(x_leaf + (size_t)(row_m0 + r) * IN_F + i0 + c * 4);
  }

  // ---- per-lane p fragments fp32: pr[mi][ks][half4] ----
  f32x4 pr[4][2][2];
#pragma unroll
  for (int mi = 0; mi < 4; ++mi) {
    int row = row_m0 + wm + mi * 16 + l15;
#pragma unroll
    for (int ks = 0; ks < 2; ++ks) {
      const f32x4* src = (const f32x4*)(p_ws + (size_t)row * NLEAF + ks * 32 + quad * 8);
      pr[mi][ks][0] = src[0];
      pr[mi][ks][1] = src[1];
    }
  }

  // ---- B-staging per-lane source offsets (XOR-rotated rows) ----
  size_t boff[4];
#pragma unroll
  for (int v = 0; v < 4; ++v) {
    int n = (wid * 4 + v) * 8 + (lane >> 3);   // 0..63
    int c = lane & 7;
    int q = (c - n) & 7;
    boff[v] = (size_t)(col_n0 + n) * NLEAF + q * 8;
  }

  f32x4 acc[4][4];
#pragma unroll
  for (int mi = 0; mi < 4; ++mi)
#pragma unroll
    for (int ni = 0; ni < 4; ++ni)
      acc[mi][ni] = (f32x4)(0.f);

  // ---- prologue: stage B tile for ii=0 ----
  {
    const __hip_bfloat16* gi = pwb + ((size_t)i0 << 15);
#pragma unroll
    for (int v = 0; v < 4; ++v) {
      __builtin_amdgcn_global_load_lds(
          (const __attribute__((address_space(1))) void*)(gi + boff[v]),
          (__attribute__((address_space(3))) void*)(&bs[0][(wid * 4 + v) * 512]),
          16, 0, 0);
    }
  }

#pragma unroll 2
  for (int ii = 0; ii < KI; ++ii) {
    __syncthreads();   // drains glds(ii) + aligns buffers

    if (ii + 1 < KI) {
      const __hip_bfloat16* gi = pwb + ((size_t)(i0 + ii + 1) << 15);
      __hip_bfloat16* dsl = &bs[(ii + 1) & 1][0];
#pragma unroll
      for (int v = 0; v < 4; ++v) {
        __builtin_amdgcn_global_load_lds(
            (const __attribute__((address_space(1))) void*)(gi + boff[v]),
            (__attribute__((address_space(3))) void*)(dsl + (wid * 4 + v) * 512),
            16, 0, 0);
      }
    }

    const __hip_bfloat16* bsc = &bs[ii & 1][0];
    float xv[4];
#pragma unroll
    for (int mi = 0; mi < 4; ++mi) xv[mi] = xs[wm + mi * 16 + l15][ii];

#pragma unroll
    for (int ks = 0; ks < 2; ++ks) {
      bf16x8 af[4];
#pragma unroll
      for (int mi = 0; mi < 4; ++mi) {
        f32x4 lo = pr[mi][ks][0] * xv[mi];
        f32x4 hi = pr[mi][ks][1] * xv[mi];
        PK8 u;
        u.v.a = __float22bfloat162_rn(make_float2(lo.x, lo.y));
        u.v.b = __float22bfloat162_rn(make_float2(lo.z, lo.w));
        u.v.c = __float22bfloat162_rn(make_float2(hi.x, hi.y));
        u.v.d = __float22bfloat162_rn(make_float2(hi.z, hi.w));
        af[mi] = u.f;
      }
#pragma unroll
      for (int ni = 0; ni < 4; ++ni) {
        int n = ni * 16 + l15;
        bf16x8 bfr = *(const bf16x8*)&bsc[n * 64 + (((ks * 4 + quad + n) & 7) << 3)];
#pragma unroll
        for (int mi = 0; mi < 4; ++mi)
          acc[mi][ni] = __builtin_amdgcn_mfma_f32_16x16x32_bf16(
              af[mi], bfr, acc[mi][ni], 0, 0, 0);
      }
    }
  }

  // ---- epilogue ----
#pragma unroll
  for (int mi = 0; mi < 4; ++mi) {
#pragma unroll
    for (int ni = 0; ni < 4; ++ni) {
      int row = row_m0 + wm + mi * 16 + quad * 4;
      int col = col_n0 + ni * 16 + l15;
      if (ATOMIC) {
        float* o0 = dst + (size_t)row * OUT_F + col;
        atomicAdd(o0,             acc[mi][ni][0]);
        atomicAdd(o0 + OUT_F,     acc[mi][ni][1]);
        atomicAdd(o0 + 2 * OUT_F, acc[mi][ni][2]);
        atomicAdd(o0 + 3 * OUT_F, acc[mi][ni][3]);
      } else {
        float* o0 = dst + ((size_t)kc << 19) + (size_t)row * OUT_F + col;
        o0[0]         = acc[mi][ni][0];
        o0[OUT_F]     = acc[mi][ni][1];
        o0[2 * OUT_F] = acc[mi][ni][2];
        o0[3 * OUT_F] = acc[mi][ni][3];
      }
    }
  }
}

// ---------------------------------------------------------------------------
// Kernel 3: out[b][o] = sum_kc parts[kc][b][o] + sum_l p[b][l]*pb[o][l]
// nparts==0: bias-only init (atomic-fallback). 512 blocks x 256 thr;
// block = 2 rows; thread = 1 row x 4 cols (one f32x4 of out).
// ---------------------------------------------------------------------------
__global__ __launch_bounds__(256, 4) void k_reduce(
    const float* __restrict__ parts, const float* __restrict__ p_ws,
    const float* __restrict__ pb, float* __restrict__ out, int nparts)
{
  __shared__ float ps_l[2 * NLEAF];
  const int t  = threadIdx.x;
  const int b0 = blockIdx.x * 2;

  if (t < 32)
    ((f32x4*)ps_l)[t] = ((const f32x4*)(p_ws + (size_t)b0 * NLEAF))[t];
  __syncthreads();

  const int row = b0 + (t >> 7);
  const int c0  = (t & 127) * 4;
  const f32x4* ps = (const f32x4*)&ps_l[(t >> 7) * NLEAF];

  f32x4 a;
#pragma unroll
  for (int jo = 0; jo < 4; ++jo) {
    const f32x4* pbo = (const f32x4*)(pb + (size_t)(c0 + jo) * NLEAF);
    f32x4 s = (f32x4)(0.f);
#pragma unroll
    for (int lv = 0; lv < 16; ++lv) s += pbo[lv] * ps[lv];
    a[jo] = s.x + s.y + s.z + s.w;
  }

#pragma unroll 8
  for (int k = 0; k < nparts; ++k)
    a += *(const f32x4*)(parts + ((size_t)k << 19) + (size_t)row * OUT_F + c0);

  *(f32x4*)(out + (size_t)row * OUT_F + c0) = a;
}

// ---------------------------------------------------------------------------
extern "C" void kernel_launch(void* const* d_in, const int* in_sizes, int n_in,
                              void* d_out, int out_size, void* d_ws, size_t ws_size,
                              hipStream_t stream) {
  const float* xg = (const float*)d_in[0];   // x_gating [1024][512]
  const float* xl = (const float*)d_in[1];   // x_leaf   [1024][512]
  const float* gw = (const float*)d_in[2];   // [512][63]
  const float* gb = (const float*)d_in[3];   // [63]
  const float* pw = (const float*)d_in[4];   // [512][512][64]
  const float* pb = (const float*)d_in[5];   // [512][64]
  float* out = (float*)d_out;

  // ws layout: pwb bf16 (33.55 MB) | p fp32 (256 KB) | parts fp32 (SK x 2 MB)
  const size_t PWB_BYTES  = (size_t)IN_F * OUT_F * NLEAF * 2;
  const size_t P_BYTES    = (size_t)B_SZ * NLEAF * 4;
  const size_t SLICE      = (size_t)B_SZ * OUT_F * 4;     // 2 MB

  __hip_bfloat16* pwb = (__hip_bfloat16*)d_ws;
  float* p_ws  = (float*)((char*)d_ws + PWB_BYTES);
  float* parts = (float*)((char*)d_ws + PWB_BYTES + P_BYTES);
  const size_t base = PWB_BYTES + P_BYTES;

  k_prep<<<dim3(B_SZ + 8192), dim3(512), 0, stream>>>(xg, gw, gb, p_ws, pw, pwb);

  if (ws_size >= base + 32 * SLICE) {
    k_gemm<32, false><<<dim3(2048), dim3(128), 0, stream>>>(xl, p_ws, pwb, parts);
    k_reduce<<<dim3(512), dim3(256), 0, stream>>>(parts, p_ws, pb, out, 32);
  } else if (ws_size >= base + 16 * SLICE) {
    k_gemm<16, false><<<dim3(1024), dim3(128), 0, stream>>>(xl, p_ws, pwb, parts);
    k_reduce<<<dim3(512), dim3(256), 0, stream>>>(parts, p_ws, pb, out, 16);
  } else if (ws_size >= base + 8 * SLICE) {
    k_gemm<8, false><<<dim3(512), dim3(128), 0, stream>>>(xl, p_ws, pwb, parts);
    k_reduce<<<dim3(512), dim3(256), 0, stream>>>(parts, p_ws, pb, out, 8);
  } else {
    k_reduce<<<dim3(512), dim3(256), 0, stream>>>(parts, p_ws, pb, out, 0);
    k_gemm<8, true><<<dim3(512), dim3(128), 0, stream>>>(xl, p_ws, pwb, out);
  }
}